// Round 15
// baseline (1345.232 us; speedup 1.0000x reference)
//
#include <hip/hip_runtime.h>

// GruBlock round 15: ABLATION ROUND + coalesced xpose2.
// Probes (template<VMODE,RPT> of R10's proven gru_fused9):
//   V0: full step (RPT=1)           -> baseline ~136us
//   V1: serial deps, NO transcendentals (RPT=4)
//   V2: full gates, NO cross-step deps (hprev=0, hB:=B0c) (RPT=8)
// Probes write d_out garbage; real kernel (R12 gru_fused11, verbatim) then
// overwrites every element. xpose2: full-line coalesced reads + XOR'd LDS.

typedef _Float16 f16x8 __attribute__((ext_vector_type(8)));
typedef __fp16   pk16  __attribute__((ext_vector_type(2)));
typedef float    f32x4 __attribute__((ext_vector_type(4)));

#define HWSTRIDE 7680   // 48*160
#define WS_WHH2_OFF 24576
#define WS_BIAS_OFF 36864
#define WS_X16_OFF  65536

__global__ void fold_weights(const float* __restrict__ conv_w,
                             const float* __restrict__ conv_b,
                             const float* __restrict__ wih_f,
                             const float* __restrict__ bih_f,
                             const float* __restrict__ bhh_f,
                             const float* __restrict__ wih_b,
                             const float* __restrict__ bih_b,
                             const float* __restrict__ bhh_b,
                             const float* __restrict__ whh_f,
                             const float* __restrict__ whh_b,
                             void* wsv)
{
    _Float16* W2   = (_Float16*)wsv;
    _Float16* whh2 = (_Float16*)((char*)wsv + WS_WHH2_OFF);
    float*    bias = (float*)((char*)wsv + WS_BIAS_OFF);
    const int idx = blockIdx.x * 256 + threadIdx.x;
    if (idx < 12288) {
        const int d = idx / 6144, r = idx % 6144, g = r / 64, c = r % 64;
        const float* wih = d ? wih_b : wih_f;
        float acc = 0.f;
        for (int o = 0; o < 64; ++o) acc += wih[g * 64 + o] * conv_w[o * 64 + c];
        W2[idx] = (_Float16)acc;
    } else if (idx < 18432) {
        const int e2 = idx - 12288;
        const int dd = e2 / 3072, rr = e2 % 3072, g = rr / 32, k = rr % 32;
        const int qq = k >> 3, ee = k & 7;
        const int jsrc = (ee < 4) ? (qq * 4 + ee) : (16 + qq * 4 + (ee - 4));
        const float* whh = dd ? whh_b : whh_f;
        whh2[e2] = (_Float16)whh[g * 32 + jsrc];
    } else if (idx < 18688) {
        const int e = idx - 18432;
        const int d = e >> 7, rr = e & 127, kind = rr >> 5, j = rr & 31;
        const float* wih = d ? wih_b : wih_f;
        const float* bih = d ? bih_b : bih_f;
        const float* bhh = d ? bhh_b : bhh_f;
        float v;
        if (kind == 0 || kind == 1) {
            const int g = j + kind * 32;
            float b2 = bih[g];
            for (int o = 0; o < 64; ++o) b2 += wih[g * 64 + o] * conv_b[o];
            v = b2 + bhh[g];
        } else if (kind == 2) {
            const int g = j + 64;
            float b2 = bih[g];
            for (int o = 0; o < 64; ++o) b2 += wih[g * 64 + o] * conv_b[o];
            v = b2;
        } else {
            v = bhh[j + 64];
        }
        bias[(d * 4 + kind) * 32 + j] = v;
    }
}

static __device__ __forceinline__ unsigned pkh(float a, float b) {
    pk16 p = __builtin_amdgcn_cvt_pkrtz(a, b);
    return __builtin_bit_cast(unsigned, p);
}

// ---------------- xpose2: coalesced (b,c,h,w) fp32 -> [slice][w][s][c] f16 ----------
__global__ __launch_bounds__(256, 2)
void xpose2(const float* __restrict__ x, _Float16* __restrict__ x16)
{
    __shared__ unsigned tile[16 * 16 * 32];   // 32 KB: [row=s*16+w][cp], XOR'd
    const int bid = blockIdx.x;
    const int wc  = bid % 10;
    const int hg  = (bid / 10) % 3;
    const int b   = bid / 30;
    const int t   = threadIdx.x;
    const float* xb = x + (size_t)b * 64 * HWSTRIDE + (size_t)(hg * 16) * 160 + wc * 16;

    float4 fA[8], fB[8];
    #pragma unroll
    for (int k = 0; k < 8; ++k) {
        const int u  = t + 256 * k;
        const int wq = u & 3, s = (u >> 2) & 15, cp = u >> 6;
        const float* p = xb + (size_t)(2 * cp) * HWSTRIDE + s * 160 + wq * 4;
        fA[k] = *(const float4*)p;
        fB[k] = *(const float4*)(p + HWSTRIDE);
    }
    #pragma unroll
    for (int k = 0; k < 8; ++k) {
        const int u  = t + 256 * k;
        const int wq = u & 3, s = (u >> 2) & 15, cp = u >> 6;
        #pragma unroll
        for (int j = 0; j < 4; ++j) {
            const int row = s * 16 + wq * 4 + j;
            tile[row * 32 + (cp ^ ((row >> 3) & 31))] =
                pkh(((const float*)&fA[k])[j], ((const float*)&fB[k])[j]);
        }
    }
    __syncthreads();
    {
        const int w = t >> 4, s = t & 15;
        const int row = s * 16 + w;
        unsigned wd[32];
        #pragma unroll
        for (int cp = 0; cp < 32; ++cp)
            wd[cp] = tile[row * 32 + (cp ^ ((row >> 3) & 31))];
        _Float16* op = x16 + ((size_t)(b * 3 + hg) * 160 + wc * 16 + w) * 1024 + s * 64;
        #pragma unroll
        for (int m = 0; m < 8; ++m)
            *(uint4*)(op + m * 8) = make_uint4(wd[4*m], wd[4*m+1], wd[4*m+2], wd[4*m+3]);
    }
}

// ---------------- ablation probe: R10 gru_fused9 with VMODE/RPT ----------------
template<int VMODE, int RPT>
__global__ __launch_bounds__(64, 1)
void gru_probe(const _Float16* __restrict__ x16,
               const void* __restrict__ wsv,
               float* __restrict__ out)
{
    const int bid   = blockIdx.x;
    const int d     = bid & 1;
    const int slice = bid >> 1;
    const int b     = slice / 3;
    const int h0    = (slice % 3) * 16;
    const int lane  = threadIdx.x;
    const int q     = lane >> 4;
    const int s16   = lane & 15;

    const _Float16* W2 = (const _Float16*)wsv + (size_t)d * 96 * 64;
    f16x8 W2A[6][2];
    #pragma unroll
    for (int gt = 0; gt < 6; ++gt)
        #pragma unroll
        for (int kt = 0; kt < 2; ++kt)
            W2A[gt][kt] = *(const f16x8*)&W2[(gt * 16 + s16) * 64 + kt * 32 + q * 8];
    const _Float16* whh2 = (const _Float16*)((const char*)wsv + WS_WHH2_OFF)
                           + (size_t)d * 96 * 32;
    f16x8 whhA[6];
    #pragma unroll
    for (int gt = 0; gt < 6; ++gt)
        whhA[gt] = *(const f16x8*)&whh2[(gt * 16 + s16) * 32 + q * 8];
    const float* bias = (const float*)((const char*)wsv + WS_BIAS_OFF) + d * 128;
    float biasC[6][4];
    #pragma unroll
    for (int gt = 0; gt < 6; ++gt)
        #pragma unroll
        for (int r = 0; r < 4; ++r)
            biasC[gt][r] = bias[(gt >> 1) * 32 + (gt & 1) * 16 + 4 * q + r];
    float bhN[2][4];
    #pragma unroll
    for (int jh = 0; jh < 2; ++jh)
        #pragma unroll
        for (int r = 0; r < 4; ++r)
            bhN[jh][r] = bias[96 + jh * 16 + 4 * q + r];

    const _Float16* xsl = x16 + (size_t)slice * 160 * 1024 + s16 * 64 + q * 8;
    float* ob = out + ((size_t)b * 64 + d * 32) * HWSTRIDE + (size_t)(h0 + s16) * 160;

    f16x8 B0r[4], B1r[4];
    auto loadB = [&](int s, f16x8& B0d, f16x8& B1d) {
        const _Float16* p = xsl + (size_t)(d ? (159 - s) : s) * 1024;
        B0d = *(const f16x8*)(p);
        B1d = *(const f16x8*)(p + 32);
    };

    #pragma unroll 1
    for (int rp = 0; rp < RPT; ++rp) {
        #pragma unroll
        for (int s0 = 0; s0 < 4; ++s0) loadB(s0, B0r[s0], B1r[s0]);
        f16x8 hB = {};
        f16x8 hB8[8];
        float hprev[8];
        #pragma unroll
        for (int uu = 0; uu < 8; ++uu) hprev[uu] = 0.f;

        #pragma unroll 1
        for (int i = 0; i < 20; ++i) {
            #pragma unroll
            for (int tt = 0; tt < 8; ++tt) {
                const int s = i * 8 + tt;
                f32x4 aR0 = {biasC[0][0], biasC[0][1], biasC[0][2], biasC[0][3]};
                f32x4 aR1 = {biasC[1][0], biasC[1][1], biasC[1][2], biasC[1][3]};
                f32x4 aZ0 = {biasC[2][0], biasC[2][1], biasC[2][2], biasC[2][3]};
                f32x4 aZ1 = {biasC[3][0], biasC[3][1], biasC[3][2], biasC[3][3]};
                f32x4 pN0 = {biasC[4][0], biasC[4][1], biasC[4][2], biasC[4][3]};
                f32x4 pN1 = {biasC[5][0], biasC[5][1], biasC[5][2], biasC[5][3]};
                f32x4 hN0 = {bhN[0][0], bhN[0][1], bhN[0][2], bhN[0][3]};
                f32x4 hN1 = {bhN[1][0], bhN[1][1], bhN[1][2], bhN[1][3]};
                const f16x8 B0c = B0r[tt & 3], B1c = B1r[tt & 3];
                aR0 = __builtin_amdgcn_mfma_f32_16x16x32_f16(W2A[0][0], B0c, aR0, 0, 0, 0);
                aR0 = __builtin_amdgcn_mfma_f32_16x16x32_f16(W2A[0][1], B1c, aR0, 0, 0, 0);
                aR1 = __builtin_amdgcn_mfma_f32_16x16x32_f16(W2A[1][0], B0c, aR1, 0, 0, 0);
                aR1 = __builtin_amdgcn_mfma_f32_16x16x32_f16(W2A[1][1], B1c, aR1, 0, 0, 0);
                aZ0 = __builtin_amdgcn_mfma_f32_16x16x32_f16(W2A[2][0], B0c, aZ0, 0, 0, 0);
                aZ0 = __builtin_amdgcn_mfma_f32_16x16x32_f16(W2A[2][1], B1c, aZ0, 0, 0, 0);
                aZ1 = __builtin_amdgcn_mfma_f32_16x16x32_f16(W2A[3][0], B0c, aZ1, 0, 0, 0);
                aZ1 = __builtin_amdgcn_mfma_f32_16x16x32_f16(W2A[3][1], B1c, aZ1, 0, 0, 0);
                pN0 = __builtin_amdgcn_mfma_f32_16x16x32_f16(W2A[4][0], B0c, pN0, 0, 0, 0);
                pN0 = __builtin_amdgcn_mfma_f32_16x16x32_f16(W2A[4][1], B1c, pN0, 0, 0, 0);
                pN1 = __builtin_amdgcn_mfma_f32_16x16x32_f16(W2A[5][0], B0c, pN1, 0, 0, 0);
                pN1 = __builtin_amdgcn_mfma_f32_16x16x32_f16(W2A[5][1], B1c, pN1, 0, 0, 0);
                aR0 = __builtin_amdgcn_mfma_f32_16x16x32_f16(whhA[0], hB, aR0, 0, 0, 0);
                aR1 = __builtin_amdgcn_mfma_f32_16x16x32_f16(whhA[1], hB, aR1, 0, 0, 0);
                aZ0 = __builtin_amdgcn_mfma_f32_16x16x32_f16(whhA[2], hB, aZ0, 0, 0, 0);
                aZ1 = __builtin_amdgcn_mfma_f32_16x16x32_f16(whhA[3], hB, aZ1, 0, 0, 0);
                hN0 = __builtin_amdgcn_mfma_f32_16x16x32_f16(whhA[4], hB, hN0, 0, 0, 0);
                hN1 = __builtin_amdgcn_mfma_f32_16x16x32_f16(whhA[5], hB, hN1, 0, 0, 0);
                {
                    int sp = s + 4; if (sp > 159) sp = 159;
                    loadB(sp, B0r[tt & 3], B1r[tt & 3]);
                }
                float hn[8];
                if constexpr (VMODE == 1) {
                    #pragma unroll
                    for (int r = 0; r < 4; ++r) {
                        hn[r]     = fmaf(0.125f, aR0[r] + aZ0[r],
                                    fmaf(0.125f, hN0[r] + pN0[r], 0.5f * hprev[r]));
                        hn[4 + r] = fmaf(0.125f, aR1[r] + aZ1[r],
                                    fmaf(0.125f, hN1[r] + pN1[r], 0.5f * hprev[4 + r]));
                    }
                } else {
                    #pragma unroll
                    for (int r = 0; r < 4; ++r) {
                        const float rr = __builtin_amdgcn_rcpf(1.f + __expf(-aR0[r]));
                        const float zz = __builtin_amdgcn_rcpf(1.f + __expf(-aZ0[r]));
                        float ta = fmaf(rr, hN0[r], pN0[r]);
                        ta = fminf(fmaxf(ta, -15.f), 15.f);
                        const float e2 = __expf(2.f * ta);
                        const float nn = (e2 - 1.f) * __builtin_amdgcn_rcpf(e2 + 1.f);
                        hn[r] = (1.f - zz) * nn + zz * hprev[r];
                    }
                    #pragma unroll
                    for (int r = 0; r < 4; ++r) {
                        const float rr = __builtin_amdgcn_rcpf(1.f + __expf(-aR1[r]));
                        const float zz = __builtin_amdgcn_rcpf(1.f + __expf(-aZ1[r]));
                        float ta = fmaf(rr, hN1[r], pN1[r]);
                        ta = fminf(fmaxf(ta, -15.f), 15.f);
                        const float e2 = __expf(2.f * ta);
                        const float nn = (e2 - 1.f) * __builtin_amdgcn_rcpf(e2 + 1.f);
                        hn[4 + r] = (1.f - zz) * nn + zz * hprev[4 + r];
                    }
                }
                uint4 hu;
                hu.x = pkh(hn[0], hn[1]); hu.y = pkh(hn[2], hn[3]);
                hu.z = pkh(hn[4], hn[5]); hu.w = pkh(hn[6], hn[7]);
                hB8[tt] = __builtin_bit_cast(f16x8, hu);
                if constexpr (VMODE == 2) {
                    asm volatile("" :: "v"(hu.x), "v"(hu.y), "v"(hu.z), "v"(hu.w));
                    hB = B0c;                       // break MFMA feedback
                    #pragma unroll
                    for (int uu = 0; uu < 8; ++uu) hprev[uu] = 0.f;  // break VALU feedback
                } else {
                    hB = __builtin_bit_cast(f16x8, hu);
                    #pragma unroll
                    for (int uu = 0; uu < 8; ++uu) hprev[uu] = hn[uu];
                }
            }
            const int w0 = d ? (152 - 8 * i) : (8 * i);
            #pragma unroll
            for (int e = 0; e < 8; ++e) {
                const int j = (e >> 2) * 16 + 4 * q + (e & 3);
                float* pw = ob + (size_t)j * HWSTRIDE + w0;
                if (d == 0) {
                    *(float4*)(pw)     = make_float4((float)hB8[0][e], (float)hB8[1][e],
                                                     (float)hB8[2][e], (float)hB8[3][e]);
                    *(float4*)(pw + 4) = make_float4((float)hB8[4][e], (float)hB8[5][e],
                                                     (float)hB8[6][e], (float)hB8[7][e]);
                } else {
                    *(float4*)(pw)     = make_float4((float)hB8[7][e], (float)hB8[6][e],
                                                     (float)hB8[5][e], (float)hB8[4][e]);
                    *(float4*)(pw + 4) = make_float4((float)hB8[3][e], (float)hB8[2][e],
                                                     (float)hB8[1][e], (float)hB8[0][e]);
                }
            }
        }
    }
}

#define BARX() do { asm volatile("s_waitcnt lgkmcnt(0)" ::: "memory"); \
                    __builtin_amdgcn_s_barrier();                      \
                    asm volatile("" ::: "memory"); } while (0)

// ---------------- real main (R12 gru_fused11, verbatim, proven 125us) ----------------
__global__ __launch_bounds__(128, 1)
void gru_fused11(const _Float16* __restrict__ x16,
                 const void* __restrict__ wsv,
                 float* __restrict__ out)
{
    __shared__ uint2 ex[2][2][4][16];

    const int bid   = blockIdx.x;
    const int d     = bid & 1;
    const int slice = bid >> 1;
    const int b     = slice / 3;
    const int h0    = (slice % 3) * 16;
    const int lane  = threadIdx.x & 63;
    const int jh    = threadIdx.x >> 6;
    const int q     = lane >> 4;
    const int s16   = lane & 15;

    const _Float16* W2 = (const _Float16*)wsv + (size_t)d * 96 * 64;
    f16x8 W2A[3][2];
    #pragma unroll
    for (int m = 0; m < 3; ++m)
        #pragma unroll
        for (int kt = 0; kt < 2; ++kt)
            W2A[m][kt] = *(const f16x8*)&W2[((2 * m + jh) * 16 + s16) * 64 + kt * 32 + q * 8];
    const _Float16* whh2 = (const _Float16*)((const char*)wsv + WS_WHH2_OFF)
                           + (size_t)d * 96 * 32;
    f16x8 whhA[3];
    #pragma unroll
    for (int m = 0; m < 3; ++m)
        whhA[m] = *(const f16x8*)&whh2[((2 * m + jh) * 16 + s16) * 32 + q * 8];

    const float* bias = (const float*)((const char*)wsv + WS_BIAS_OFF) + d * 128;
    const int jb = jh * 16 + 4 * q;
    float bR[4], bZ[4], bPN[4], bHN[4];
    #pragma unroll
    for (int r = 0; r < 4; ++r) {
        bR[r]  = bias[      jb + r];
        bZ[r]  = bias[ 32 + jb + r];
        bPN[r] = bias[ 64 + jb + r];
        bHN[r] = bias[ 96 + jb + r];
    }

    const _Float16* xsl = x16 + (size_t)slice * 160 * 1024 + s16 * 64 + q * 8;
    float* ob = out + ((size_t)b * 64 + d * 32) * HWSTRIDE + (size_t)(h0 + s16) * 160;

    f16x8 rb0[4], rb1[4];
    auto ldB = [&](int s, int slot) {
        const _Float16* p = xsl + (size_t)(d ? (159 - s) : s) * 1024;
        rb0[slot] = *(const f16x8*)(p);
        rb1[slot] = *(const f16x8*)(p + 32);
    };
    ldB(0, 0); ldB(1, 1); ldB(2, 2); ldB(3, 3);

    f16x8 hB = {};
    float hp[4] = {0.f, 0.f, 0.f, 0.f};
    float hh[4][16];

    #pragma unroll 1
    for (int i = 0; i < 10; ++i) {
        #pragma unroll
        for (int tt = 0; tt < 16; ++tt) {
            const int s = i * 16 + tt;
            const int slot = s & 3;
            const f16x8 b0 = rb0[slot], b1 = rb1[slot];
            f32x4 aR  = {bR[0],  bR[1],  bR[2],  bR[3]};
            f32x4 aZ  = {bZ[0],  bZ[1],  bZ[2],  bZ[3]};
            f32x4 aPN = {bPN[0], bPN[1], bPN[2], bPN[3]};
            f32x4 aHN = {bHN[0], bHN[1], bHN[2], bHN[3]};
            aR  = __builtin_amdgcn_mfma_f32_16x16x32_f16(W2A[0][0], b0, aR,  0, 0, 0);
            aR  = __builtin_amdgcn_mfma_f32_16x16x32_f16(W2A[0][1], b1, aR,  0, 0, 0);
            aZ  = __builtin_amdgcn_mfma_f32_16x16x32_f16(W2A[1][0], b0, aZ,  0, 0, 0);
            aZ  = __builtin_amdgcn_mfma_f32_16x16x32_f16(W2A[1][1], b1, aZ,  0, 0, 0);
            aPN = __builtin_amdgcn_mfma_f32_16x16x32_f16(W2A[2][0], b0, aPN, 0, 0, 0);
            aPN = __builtin_amdgcn_mfma_f32_16x16x32_f16(W2A[2][1], b1, aPN, 0, 0, 0);
            aR  = __builtin_amdgcn_mfma_f32_16x16x32_f16(whhA[0], hB, aR,  0, 0, 0);
            aZ  = __builtin_amdgcn_mfma_f32_16x16x32_f16(whhA[1], hB, aZ,  0, 0, 0);
            aHN = __builtin_amdgcn_mfma_f32_16x16x32_f16(whhA[2], hB, aHN, 0, 0, 0);
            {
                int sp = s + 4; if (sp > 159) sp = 159;
                ldB(sp, slot);
            }
            float hn[4];
            #pragma unroll
            for (int r = 0; r < 4; ++r) {
                const float rr = __builtin_amdgcn_rcpf(1.f + __expf(-aR[r]));
                const float zz = __builtin_amdgcn_rcpf(1.f + __expf(-aZ[r]));
                float ta = fmaf(rr, aHN[r], aPN[r]);
                ta = fminf(fmaxf(ta, -15.f), 15.f);
                const float e2 = __expf(2.f * ta);
                const float nn = (e2 - 1.f) * __builtin_amdgcn_rcpf(e2 + 1.f);
                hn[r] = fmaf(zz, hp[r] - nn, nn);
                hh[r][tt] = hn[r];
                hp[r] = hn[r];
            }
            uint2 own;
            own.x = pkh(hn[0], hn[1]);
            own.y = pkh(hn[2], hn[3]);
            ex[s & 1][jh][q][s16] = own;
            BARX();
            const uint2 oth = ex[s & 1][1 - jh][q][s16];
            uint4 hu;
            if (jh == 0) { hu.x = own.x; hu.y = own.y; hu.z = oth.x; hu.w = oth.y; }
            else         { hu.x = oth.x; hu.y = oth.y; hu.z = own.x; hu.w = own.y; }
            hB = __builtin_bit_cast(f16x8, hu);
        }
        {
            const int w0 = d ? (144 - 16 * i) : (16 * i);
            #pragma unroll
            for (int r = 0; r < 4; ++r) {
                const int j = jh * 16 + 4 * q + r;
                float* pw = ob + (size_t)j * HWSTRIDE + w0;
                if (d == 0) {
                    #pragma unroll
                    for (int m = 0; m < 4; ++m)
                        *(float4*)(pw + 4 * m) =
                            make_float4(hh[r][4*m], hh[r][4*m+1], hh[r][4*m+2], hh[r][4*m+3]);
                } else {
                    #pragma unroll
                    for (int m = 0; m < 4; ++m)
                        *(float4*)(pw + 4 * m) =
                            make_float4(hh[r][15-4*m], hh[r][14-4*m], hh[r][13-4*m], hh[r][12-4*m]);
                }
            }
        }
    }
}

// ---------------- fallback (R9, proven) ----------------
__global__ __launch_bounds__(128, 1)
void gru_fused8(const float* __restrict__ x,
                const void* __restrict__ wsv,
                float* __restrict__ out)
{
    __shared__ __align__(16) _Float16 xt[1024 * 8];
    __shared__ __align__(16) _Float16 spre[2 * 8 * 16 * 96];

    const int bid  = blockIdx.x;
    const int d    = bid / 192;
    const int g    = bid % 192;
    const int b    = g / 3;
    const int h0   = (g % 3) * 16;
    const int lane = threadIdx.x & 63;
    const int wave = threadIdx.x >> 6;
    const int sw   = bid & 1;
    const int q    = lane >> 4;
    const int s16  = lane & 15;

    const float* xb = x + (size_t)b * 64 * HWSTRIDE + (size_t)h0 * 160;

    if (wave != sw) {
        const _Float16* W2 = (const _Float16*)wsv + (size_t)d * 96 * 64;
        f16x8 W2A[6][2];
        #pragma unroll
        for (int gt = 0; gt < 6; ++gt)
            #pragma unroll
            for (int kt = 0; kt < 2; ++kt)
                W2A[gt][kt] = *(const f16x8*)&W2[(gt * 16 + s16) * 64 + kt * 32 + q * 8];
        const float* bias = (const float*)((const char*)wsv + WS_BIAS_OFF) + d * 128;
        float biasC[6][4];
        #pragma unroll
        for (int gt = 0; gt < 6; ++gt)
            #pragma unroll
            for (int r = 0; r < 4; ++r)
                biasC[gt][r] = bias[(gt >> 1) * 32 + (gt & 1) * 16 + 4 * q + r];

        float4 pf[32];
        auto load_win = [&](int wi) {
            const int w0 = d ? (152 - 8 * wi) : (8 * wi);
            #pragma unroll
            for (int k = 0; k < 16; ++k) {
                const int row = lane + 64 * k;
                const float* p = xb + (size_t)(row >> 4) * HWSTRIDE + (row & 15) * 160 + w0;
                pf[2 * k]     = *(const float4*)p;
                pf[2 * k + 1] = *(const float4*)(p + 4);
            }
        };
        auto write_xt = [&]() {
            #pragma unroll
            for (int k = 0; k < 16; ++k) {
                const int row = lane + 64 * k;
                uint4 v;
                v.x = pkh(pf[2*k].x,   pf[2*k].y);
                v.y = pkh(pf[2*k].z,   pf[2*k].w);
                v.z = pkh(pf[2*k+1].x, pf[2*k+1].y);
                v.w = pkh(pf[2*k+1].z, pf[2*k+1].w);
                *(uint4*)&xt[row * 8] = v;
            }
        };
        auto project = [&](int wi) {
            _Float16* sp = &spre[(wi & 1) * 12288];
            for (int tt = 0; tt < 8; ++tt) {
                const int wl = d ? (7 - tt) : tt;
                const int base0 = (q * 8) * 128 + s16 * 8 + wl;
                f16x8 B0, B1;
                #pragma unroll
                for (int e = 0; e < 8; ++e) {
                    B0[e] = xt[base0 + e * 128];
                    B1[e] = xt[base0 + e * 128 + 4096];
                }
                #pragma unroll
                for (int gt = 0; gt < 6; ++gt) {
                    f32x4 acc = {biasC[gt][0], biasC[gt][1], biasC[gt][2], biasC[gt][3]};
                    acc = __builtin_amdgcn_mfma_f32_16x16x32_f16(W2A[gt][0], B0, acc, 0, 0, 0);
                    acc = __builtin_amdgcn_mfma_f32_16x16x32_f16(W2A[gt][1], B1, acc, 0, 0, 0);
                    uint2 v; v.x = pkh(acc[0], acc[1]); v.y = pkh(acc[2], acc[3]);
                    const int col = (gt * 16 + 4 * q) ^ ((s16 & 7) << 2);
                    *(uint2*)&sp[(tt * 16 + s16) * 96 + col] = v;
                }
            }
        };

        load_win(0);
        #pragma unroll 1
        for (int i = 0; i < 20; ++i) {
            write_xt();
            project(i);
            if (i + 1 < 20) load_win(i + 1);
            BARX();
        }
    } else {
        const _Float16* whh2 = (const _Float16*)((const char*)wsv + WS_WHH2_OFF)
                               + (size_t)d * 96 * 32;
        f16x8 whhA[6];
        #pragma unroll
        for (int gt = 0; gt < 6; ++gt)
            whhA[gt] = *(const f16x8*)&whh2[(gt * 16 + s16) * 32 + q * 8];
        const float* bias = (const float*)((const char*)wsv + WS_BIAS_OFF) + d * 128;
        float bhN[2][4];
        #pragma unroll
        for (int jh = 0; jh < 2; ++jh)
            #pragma unroll
            for (int r = 0; r < 4; ++r)
                bhN[jh][r] = bias[96 + jh * 16 + 4 * q + r];

        float* ob = out + ((size_t)b * 64 + d * 32) * HWSTRIDE + (size_t)(h0 + s16) * 160;
        f16x8 hB = {};
        f16x8 hB8[8];
        float hprev[8];
        #pragma unroll
        for (int uu = 0; uu < 8; ++uu) hprev[uu] = 0.f;

        int spcol[6];
        #pragma unroll
        for (int gt = 0; gt < 6; ++gt)
            spcol[gt] = (gt * 16 + 4 * q) ^ ((s16 & 7) << 2);

        typedef _Float16 f16x4l __attribute__((ext_vector_type(4)));
        #pragma unroll 1
        for (int i = 0; i < 20; ++i) {
            BARX();
            const _Float16* sp = &spre[(i & 1) * 12288];
            f16x4l pg[4][6];
            #pragma unroll
            for (int tt = 0; tt < 8; ++tt) {
                if ((tt & 3) == 0) {
                    #pragma unroll
                    for (int t4 = 0; t4 < 4; ++t4)
                        #pragma unroll
                        for (int gt = 0; gt < 6; ++gt)
                            pg[t4][gt] = *(const f16x4l*)
                                &sp[((tt + t4) * 16 + s16) * 96 + spcol[gt]];
                }
                const f16x4l p0 = pg[tt & 3][0], p1 = pg[tt & 3][1];
                const f16x4l p2 = pg[tt & 3][2], p3 = pg[tt & 3][3];
                const f16x4l p4 = pg[tt & 3][4], p5 = pg[tt & 3][5];
                f32x4 aR0 = {(float)p0[0], (float)p0[1], (float)p0[2], (float)p0[3]};
                f32x4 aR1 = {(float)p1[0], (float)p1[1], (float)p1[2], (float)p1[3]};
                f32x4 aZ0 = {(float)p2[0], (float)p2[1], (float)p2[2], (float)p2[3]};
                f32x4 aZ1 = {(float)p3[0], (float)p3[1], (float)p3[2], (float)p3[3]};
                f32x4 aN0 = {bhN[0][0], bhN[0][1], bhN[0][2], bhN[0][3]};
                f32x4 aN1 = {bhN[1][0], bhN[1][1], bhN[1][2], bhN[1][3]};
                aR0 = __builtin_amdgcn_mfma_f32_16x16x32_f16(whhA[0], hB, aR0, 0, 0, 0);
                aR1 = __builtin_amdgcn_mfma_f32_16x16x32_f16(whhA[1], hB, aR1, 0, 0, 0);
                aZ0 = __builtin_amdgcn_mfma_f32_16x16x32_f16(whhA[2], hB, aZ0, 0, 0, 0);
                aZ1 = __builtin_amdgcn_mfma_f32_16x16x32_f16(whhA[3], hB, aZ1, 0, 0, 0);
                aN0 = __builtin_amdgcn_mfma_f32_16x16x32_f16(whhA[4], hB, aN0, 0, 0, 0);
                aN1 = __builtin_amdgcn_mfma_f32_16x16x32_f16(whhA[5], hB, aN1, 0, 0, 0);
                float hn[8];
                #pragma unroll
                for (int r = 0; r < 4; ++r) {
                    const float rr = __builtin_amdgcn_rcpf(1.f + __expf(-aR0[r]));
                    const float zz = __builtin_amdgcn_rcpf(1.f + __expf(-aZ0[r]));
                    float ta = fmaf(rr, aN0[r], (float)p4[r]);
                    ta = fminf(fmaxf(ta, -15.f), 15.f);
                    const float e2 = __expf(2.f * ta);
                    const float nn = (e2 - 1.f) * __builtin_amdgcn_rcpf(e2 + 1.f);
                    hn[r] = (1.f - zz) * nn + zz * hprev[r];
                }
                #pragma unroll
                for (int r = 0; r < 4; ++r) {
                    const float rr = __builtin_amdgcn_rcpf(1.f + __expf(-aR1[r]));
                    const float zz = __builtin_amdgcn_rcpf(1.f + __expf(-aZ1[r]));
                    float ta = fmaf(rr, aN1[r], (float)p5[r]);
                    ta = fminf(fmaxf(ta, -15.f), 15.f);
                    const float e2 = __expf(2.f * ta);
                    const float nn = (e2 - 1.f) * __builtin_amdgcn_rcpf(e2 + 1.f);
                    hn[4 + r] = (1.f - zz) * nn + zz * hprev[4 + r];
                }
                {
                    uint4 hu;
                    hu.x = pkh(hn[0], hn[1]); hu.y = pkh(hn[2], hn[3]);
                    hu.z = pkh(hn[4], hn[5]); hu.w = pkh(hn[6], hn[7]);
                    hB = __builtin_bit_cast(f16x8, hu);
                }
                hB8[tt] = hB;
                #pragma unroll
                for (int uu = 0; uu < 8; ++uu) hprev[uu] = hn[uu];
            }
            {
                const int w0 = d ? (152 - 8 * i) : (8 * i);
                #pragma unroll
                for (int e = 0; e < 8; ++e) {
                    const int j = (e >> 2) * 16 + 4 * q + (e & 3);
                    float* pw = ob + (size_t)j * HWSTRIDE + w0;
                    if (d == 0) {
                        *(float4*)(pw) = make_float4((float)hB8[0][e], (float)hB8[1][e],
                                                     (float)hB8[2][e], (float)hB8[3][e]);
                        *(float4*)(pw + 4) = make_float4((float)hB8[4][e], (float)hB8[5][e],
                                                         (float)hB8[6][e], (float)hB8[7][e]);
                    } else {
                        *(float4*)(pw) = make_float4((float)hB8[7][e], (float)hB8[6][e],
                                                     (float)hB8[5][e], (float)hB8[4][e]);
                        *(float4*)(pw + 4) = make_float4((float)hB8[3][e], (float)hB8[2][e],
                                                         (float)hB8[1][e], (float)hB8[0][e]);
                    }
                }
            }
        }
    }
}

extern "C" void kernel_launch(void* const* d_in, const int* in_sizes, int n_in,
                              void* d_out, int out_size, void* d_ws, size_t ws_size,
                              hipStream_t stream) {
    (void)in_sizes; (void)n_in; (void)out_size;
    fold_weights<<<dim3(74), dim3(256), 0, stream>>>(
        (const float*)d_in[1],  // conv_w
        (const float*)d_in[2],  // conv_b
        (const float*)d_in[3],  // wih_f
        (const float*)d_in[5],  // bih_f
        (const float*)d_in[6],  // bhh_f
        (const float*)d_in[7],  // wih_b
        (const float*)d_in[9],  // bih_b
        (const float*)d_in[10], // bhh_b
        (const float*)d_in[4],  // whh_f
        (const float*)d_in[8],  // whh_b
        d_ws);
    const size_t need = (size_t)WS_X16_OFF + (size_t)192 * 160 * 1024 * 2;
    if (ws_size >= need) {
        _Float16* x16 = (_Float16*)((char*)d_ws + WS_X16_OFF);
        xpose2<<<dim3(1920), dim3(256), 0, stream>>>((const float*)d_in[0], x16);
        // ---- ablation probes (write d_out garbage; overwritten below) ----
        gru_probe<0, 1><<<dim3(384), dim3(64), 0, stream>>>(x16, d_ws, (float*)d_out);
        gru_probe<1, 4><<<dim3(384), dim3(64), 0, stream>>>(x16, d_ws, (float*)d_out);
        gru_probe<2, 8><<<dim3(384), dim3(64), 0, stream>>>(x16, d_ws, (float*)d_out);
        // ---- real kernel: overwrites every output element ----
        gru_fused11<<<dim3(384), dim3(128), 0, stream>>>(x16, d_ws, (float*)d_out);
    } else {
        gru_fused8<<<dim3(384), dim3(128), 0, stream>>>(
            (const float*)d_in[0], d_ws, (float*)d_out);
    }
}

// Round 16
// 183.675 us; speedup vs baseline: 7.3240x; 7.3240x over previous
//
#include <hip/hip_runtime.h>

// GruBlock round 16: stage-batched gate transcendentals on the proven R10 base.
// Ablation (R15) showed gates' trans ops cost 89/136 us, mostly exposed
// dependent-chain latency. Fix: batch all 8 h-values per trans stage so the
// 48 quarter-rate ops issue back-to-back (issue-bound, not latency-bound).
// Everything else verbatim-proven: x16 pre-transpose (xpose2), B-frag ring,
// 18-MFMA chained step, register-recycled h, 32B store windows.

typedef _Float16 f16x8 __attribute__((ext_vector_type(8)));
typedef __fp16   pk16  __attribute__((ext_vector_type(2)));
typedef float    f32x4 __attribute__((ext_vector_type(4)));

#define HWSTRIDE 7680   // 48*160
#define WS_WHH2_OFF 24576
#define WS_BIAS_OFF 36864
#define WS_X16_OFF  65536

__global__ void fold_weights(const float* __restrict__ conv_w,
                             const float* __restrict__ conv_b,
                             const float* __restrict__ wih_f,
                             const float* __restrict__ bih_f,
                             const float* __restrict__ bhh_f,
                             const float* __restrict__ wih_b,
                             const float* __restrict__ bih_b,
                             const float* __restrict__ bhh_b,
                             const float* __restrict__ whh_f,
                             const float* __restrict__ whh_b,
                             void* wsv)
{
    _Float16* W2   = (_Float16*)wsv;
    _Float16* whh2 = (_Float16*)((char*)wsv + WS_WHH2_OFF);
    float*    bias = (float*)((char*)wsv + WS_BIAS_OFF);
    const int idx = blockIdx.x * 256 + threadIdx.x;
    if (idx < 12288) {
        const int d = idx / 6144, r = idx % 6144, g = r / 64, c = r % 64;
        const float* wih = d ? wih_b : wih_f;
        float acc = 0.f;
        for (int o = 0; o < 64; ++o) acc += wih[g * 64 + o] * conv_w[o * 64 + c];
        W2[idx] = (_Float16)acc;
    } else if (idx < 18432) {
        const int e2 = idx - 12288;
        const int dd = e2 / 3072, rr = e2 % 3072, g = rr / 32, k = rr % 32;
        const int qq = k >> 3, ee = k & 7;
        const int jsrc = (ee < 4) ? (qq * 4 + ee) : (16 + qq * 4 + (ee - 4));
        const float* whh = dd ? whh_b : whh_f;
        whh2[e2] = (_Float16)whh[g * 32 + jsrc];
    } else if (idx < 18688) {
        const int e = idx - 18432;
        const int d = e >> 7, rr = e & 127, kind = rr >> 5, j = rr & 31;
        const float* wih = d ? wih_b : wih_f;
        const float* bih = d ? bih_b : bih_f;
        const float* bhh = d ? bhh_b : bhh_f;
        float v;
        if (kind == 0 || kind == 1) {
            const int g = j + kind * 32;
            float b2 = bih[g];
            for (int o = 0; o < 64; ++o) b2 += wih[g * 64 + o] * conv_b[o];
            v = b2 + bhh[g];
        } else if (kind == 2) {
            const int g = j + 64;
            float b2 = bih[g];
            for (int o = 0; o < 64; ++o) b2 += wih[g * 64 + o] * conv_b[o];
            v = b2;
        } else {
            v = bhh[j + 64];
        }
        bias[(d * 4 + kind) * 32 + j] = v;
    }
}

static __device__ __forceinline__ unsigned pkh(float a, float b) {
    pk16 p = __builtin_amdgcn_cvt_pkrtz(a, b);
    return __builtin_bit_cast(unsigned, p);
}

// ---------------- xpose2: coalesced (b,c,h,w) fp32 -> [slice][w][s][c] f16 ----------
__global__ __launch_bounds__(256, 2)
void xpose2(const float* __restrict__ x, _Float16* __restrict__ x16)
{
    __shared__ unsigned tile[16 * 16 * 32];   // 32 KB: [row=s*16+w][cp], XOR'd
    const int bid = blockIdx.x;
    const int wc  = bid % 10;
    const int hg  = (bid / 10) % 3;
    const int b   = bid / 30;
    const int t   = threadIdx.x;
    const float* xb = x + (size_t)b * 64 * HWSTRIDE + (size_t)(hg * 16) * 160 + wc * 16;

    float4 fA[8], fB[8];
    #pragma unroll
    for (int k = 0; k < 8; ++k) {
        const int u  = t + 256 * k;
        const int wq = u & 3, s = (u >> 2) & 15, cp = u >> 6;
        const float* p = xb + (size_t)(2 * cp) * HWSTRIDE + s * 160 + wq * 4;
        fA[k] = *(const float4*)p;
        fB[k] = *(const float4*)(p + HWSTRIDE);
    }
    #pragma unroll
    for (int k = 0; k < 8; ++k) {
        const int u  = t + 256 * k;
        const int wq = u & 3, s = (u >> 2) & 15, cp = u >> 6;
        #pragma unroll
        for (int j = 0; j < 4; ++j) {
            const int row = s * 16 + wq * 4 + j;
            tile[row * 32 + (cp ^ ((row >> 3) & 31))] =
                pkh(((const float*)&fA[k])[j], ((const float*)&fB[k])[j]);
        }
    }
    __syncthreads();
    {
        const int w = t >> 4, s = t & 15;
        const int row = s * 16 + w;
        unsigned wd[32];
        #pragma unroll
        for (int cp = 0; cp < 32; ++cp)
            wd[cp] = tile[row * 32 + (cp ^ ((row >> 3) & 31))];
        _Float16* op = x16 + ((size_t)(b * 3 + hg) * 160 + wc * 16 + w) * 1024 + s * 64;
        #pragma unroll
        for (int m = 0; m < 8; ++m)
            *(uint4*)(op + m * 8) = make_uint4(wd[4*m], wd[4*m+1], wd[4*m+2], wd[4*m+3]);
    }
}

// ---------------- main: R10 base + stage-batched gates ----------------
__global__ __launch_bounds__(64, 1)
void gru_fused14(const _Float16* __restrict__ x16,
                 const void* __restrict__ wsv,
                 float* __restrict__ out)
{
    const int bid   = blockIdx.x;        // 0..383
    const int d     = bid & 1;
    const int slice = bid >> 1;          // 0..191
    const int b     = slice / 3;
    const int h0    = (slice % 3) * 16;
    const int lane  = threadIdx.x;
    const int q     = lane >> 4;
    const int s16   = lane & 15;

    const _Float16* W2 = (const _Float16*)wsv + (size_t)d * 96 * 64;
    f16x8 W2A[6][2];
    #pragma unroll
    for (int gt = 0; gt < 6; ++gt)
        #pragma unroll
        for (int kt = 0; kt < 2; ++kt)
            W2A[gt][kt] = *(const f16x8*)&W2[(gt * 16 + s16) * 64 + kt * 32 + q * 8];
    const _Float16* whh2 = (const _Float16*)((const char*)wsv + WS_WHH2_OFF)
                           + (size_t)d * 96 * 32;
    f16x8 whhA[6];
    #pragma unroll
    for (int gt = 0; gt < 6; ++gt)
        whhA[gt] = *(const f16x8*)&whh2[(gt * 16 + s16) * 32 + q * 8];
    const float* bias = (const float*)((const char*)wsv + WS_BIAS_OFF) + d * 128;
    float biasC[6][4];
    #pragma unroll
    for (int gt = 0; gt < 6; ++gt)
        #pragma unroll
        for (int r = 0; r < 4; ++r)
            biasC[gt][r] = bias[(gt >> 1) * 32 + (gt & 1) * 16 + 4 * q + r];
    float bhN[2][4];
    #pragma unroll
    for (int jh = 0; jh < 2; ++jh)
        #pragma unroll
        for (int r = 0; r < 4; ++r)
            bhN[jh][r] = bias[96 + jh * 16 + 4 * q + r];

    const _Float16* xsl = x16 + (size_t)slice * 160 * 1024 + s16 * 64 + q * 8;
    float* ob = out + ((size_t)b * 64 + d * 32) * HWSTRIDE + (size_t)(h0 + s16) * 160;

    f16x8 B0r[4], B1r[4];
    auto loadB = [&](int s, f16x8& B0d, f16x8& B1d) {
        const _Float16* p = xsl + (size_t)(d ? (159 - s) : s) * 1024;
        B0d = *(const f16x8*)(p);
        B1d = *(const f16x8*)(p + 32);
    };
    #pragma unroll
    for (int s0 = 0; s0 < 4; ++s0) loadB(s0, B0r[s0], B1r[s0]);

    f16x8 hB = {};
    f16x8 hB8[8];
    float hprev[8];
    #pragma unroll
    for (int uu = 0; uu < 8; ++uu) hprev[uu] = 0.f;

    #pragma unroll 1
    for (int i = 0; i < 20; ++i) {
        #pragma unroll
        for (int tt = 0; tt < 8; ++tt) {
            const int s = i * 8 + tt;
            f32x4 aR0 = {biasC[0][0], biasC[0][1], biasC[0][2], biasC[0][3]};
            f32x4 aR1 = {biasC[1][0], biasC[1][1], biasC[1][2], biasC[1][3]};
            f32x4 aZ0 = {biasC[2][0], biasC[2][1], biasC[2][2], biasC[2][3]};
            f32x4 aZ1 = {biasC[3][0], biasC[3][1], biasC[3][2], biasC[3][3]};
            f32x4 pN0 = {biasC[4][0], biasC[4][1], biasC[4][2], biasC[4][3]};
            f32x4 pN1 = {biasC[5][0], biasC[5][1], biasC[5][2], biasC[5][3]};
            f32x4 hN0 = {bhN[0][0], bhN[0][1], bhN[0][2], bhN[0][3]};
            f32x4 hN1 = {bhN[1][0], bhN[1][1], bhN[1][2], bhN[1][3]};
            const f16x8 B0c = B0r[tt & 3], B1c = B1r[tt & 3];
            aR0 = __builtin_amdgcn_mfma_f32_16x16x32_f16(W2A[0][0], B0c, aR0, 0, 0, 0);
            aR0 = __builtin_amdgcn_mfma_f32_16x16x32_f16(W2A[0][1], B1c, aR0, 0, 0, 0);
            aR1 = __builtin_amdgcn_mfma_f32_16x16x32_f16(W2A[1][0], B0c, aR1, 0, 0, 0);
            aR1 = __builtin_amdgcn_mfma_f32_16x16x32_f16(W2A[1][1], B1c, aR1, 0, 0, 0);
            aZ0 = __builtin_amdgcn_mfma_f32_16x16x32_f16(W2A[2][0], B0c, aZ0, 0, 0, 0);
            aZ0 = __builtin_amdgcn_mfma_f32_16x16x32_f16(W2A[2][1], B1c, aZ0, 0, 0, 0);
            aZ1 = __builtin_amdgcn_mfma_f32_16x16x32_f16(W2A[3][0], B0c, aZ1, 0, 0, 0);
            aZ1 = __builtin_amdgcn_mfma_f32_16x16x32_f16(W2A[3][1], B1c, aZ1, 0, 0, 0);
            pN0 = __builtin_amdgcn_mfma_f32_16x16x32_f16(W2A[4][0], B0c, pN0, 0, 0, 0);
            pN0 = __builtin_amdgcn_mfma_f32_16x16x32_f16(W2A[4][1], B1c, pN0, 0, 0, 0);
            pN1 = __builtin_amdgcn_mfma_f32_16x16x32_f16(W2A[5][0], B0c, pN1, 0, 0, 0);
            pN1 = __builtin_amdgcn_mfma_f32_16x16x32_f16(W2A[5][1], B1c, pN1, 0, 0, 0);
            aR0 = __builtin_amdgcn_mfma_f32_16x16x32_f16(whhA[0], hB, aR0, 0, 0, 0);
            aR1 = __builtin_amdgcn_mfma_f32_16x16x32_f16(whhA[1], hB, aR1, 0, 0, 0);
            aZ0 = __builtin_amdgcn_mfma_f32_16x16x32_f16(whhA[2], hB, aZ0, 0, 0, 0);
            aZ1 = __builtin_amdgcn_mfma_f32_16x16x32_f16(whhA[3], hB, aZ1, 0, 0, 0);
            hN0 = __builtin_amdgcn_mfma_f32_16x16x32_f16(whhA[4], hB, hN0, 0, 0, 0);
            hN1 = __builtin_amdgcn_mfma_f32_16x16x32_f16(whhA[5], hB, hN1, 0, 0, 0);
            {
                int sp = s + 4; if (sp > 159) sp = 159;
                loadB(sp, B0r[tt & 3], B1r[tt & 3]);
            }
            // ---- gates: stage-batched across all 8 h-values ----
            float xr[8], xz[8], pn[8], hv[8];
            #pragma unroll
            for (int r = 0; r < 4; ++r) {
                xr[r] = aR0[r]; xr[4 + r] = aR1[r];
                xz[r] = aZ0[r]; xz[4 + r] = aZ1[r];
                pn[r] = pN0[r]; pn[4 + r] = pN1[r];
                hv[r] = hN0[r]; hv[4 + r] = hN1[r];
            }
            float er[8], ez[8], rr[8], zz[8], ta[8], e2[8], nn[8], hn[8];
            #pragma unroll
            for (int k = 0; k < 8; ++k) er[k] = __expf(-xr[k]);
            #pragma unroll
            for (int k = 0; k < 8; ++k) ez[k] = __expf(-xz[k]);
            #pragma unroll
            for (int k = 0; k < 8; ++k) rr[k] = __builtin_amdgcn_rcpf(1.f + er[k]);
            #pragma unroll
            for (int k = 0; k < 8; ++k) zz[k] = __builtin_amdgcn_rcpf(1.f + ez[k]);
            #pragma unroll
            for (int k = 0; k < 8; ++k) {
                const float t2 = fmaf(rr[k], hv[k], pn[k]);
                ta[k] = fminf(fmaxf(t2, -15.f), 15.f);
            }
            #pragma unroll
            for (int k = 0; k < 8; ++k) e2[k] = __expf(2.f * ta[k]);
            #pragma unroll
            for (int k = 0; k < 8; ++k)
                nn[k] = fmaf(-2.f, __builtin_amdgcn_rcpf(e2[k] + 1.f), 1.f);
            #pragma unroll
            for (int k = 0; k < 8; ++k)
                hn[k] = fmaf(zz[k], hprev[k] - nn[k], nn[k]);

            uint4 hu;
            hu.x = pkh(hn[0], hn[1]); hu.y = pkh(hn[2], hn[3]);
            hu.z = pkh(hn[4], hn[5]); hu.w = pkh(hn[6], hn[7]);
            hB = __builtin_bit_cast(f16x8, hu);
            hB8[tt] = hB;
            #pragma unroll
            for (int uu = 0; uu < 8; ++uu) hprev[uu] = hn[uu];
        }
        // ---- store window i: 32 B per out row ----
        const int w0 = d ? (152 - 8 * i) : (8 * i);
        #pragma unroll
        for (int e = 0; e < 8; ++e) {
            const int j = (e >> 2) * 16 + 4 * q + (e & 3);
            float* pw = ob + (size_t)j * HWSTRIDE + w0;
            if (d == 0) {
                *(float4*)(pw)     = make_float4((float)hB8[0][e], (float)hB8[1][e],
                                                 (float)hB8[2][e], (float)hB8[3][e]);
                *(float4*)(pw + 4) = make_float4((float)hB8[4][e], (float)hB8[5][e],
                                                 (float)hB8[6][e], (float)hB8[7][e]);
            } else {
                *(float4*)(pw)     = make_float4((float)hB8[7][e], (float)hB8[6][e],
                                                 (float)hB8[5][e], (float)hB8[4][e]);
                *(float4*)(pw + 4) = make_float4((float)hB8[3][e], (float)hB8[2][e],
                                                 (float)hB8[1][e], (float)hB8[0][e]);
            }
        }
    }
}

#define BARX() do { asm volatile("s_waitcnt lgkmcnt(0)" ::: "memory"); \
                    __builtin_amdgcn_s_barrier();                      \
                    asm volatile("" ::: "memory"); } while (0)

// ---------------- fallback (R9, proven) ----------------
__global__ __launch_bounds__(128, 1)
void gru_fused8(const float* __restrict__ x,
                const void* __restrict__ wsv,
                float* __restrict__ out)
{
    __shared__ __align__(16) _Float16 xt[1024 * 8];
    __shared__ __align__(16) _Float16 spre[2 * 8 * 16 * 96];

    const int bid  = blockIdx.x;
    const int d    = bid / 192;
    const int g    = bid % 192;
    const int b    = g / 3;
    const int h0   = (g % 3) * 16;
    const int lane = threadIdx.x & 63;
    const int wave = threadIdx.x >> 6;
    const int sw   = bid & 1;
    const int q    = lane >> 4;
    const int s16  = lane & 15;

    const float* xb = x + (size_t)b * 64 * HWSTRIDE + (size_t)h0 * 160;

    if (wave != sw) {
        const _Float16* W2 = (const _Float16*)wsv + (size_t)d * 96 * 64;
        f16x8 W2A[6][2];
        #pragma unroll
        for (int gt = 0; gt < 6; ++gt)
            #pragma unroll
            for (int kt = 0; kt < 2; ++kt)
                W2A[gt][kt] = *(const f16x8*)&W2[(gt * 16 + s16) * 64 + kt * 32 + q * 8];
        const float* bias = (const float*)((const char*)wsv + WS_BIAS_OFF) + d * 128;
        float biasC[6][4];
        #pragma unroll
        for (int gt = 0; gt < 6; ++gt)
            #pragma unroll
            for (int r = 0; r < 4; ++r)
                biasC[gt][r] = bias[(gt >> 1) * 32 + (gt & 1) * 16 + 4 * q + r];

        float4 pf[32];
        auto load_win = [&](int wi) {
            const int w0 = d ? (152 - 8 * wi) : (8 * wi);
            #pragma unroll
            for (int k = 0; k < 16; ++k) {
                const int row = lane + 64 * k;
                const float* p = xb + (size_t)(row >> 4) * HWSTRIDE + (row & 15) * 160 + w0;
                pf[2 * k]     = *(const float4*)p;
                pf[2 * k + 1] = *(const float4*)(p + 4);
            }
        };
        auto write_xt = [&]() {
            #pragma unroll
            for (int k = 0; k < 16; ++k) {
                const int row = lane + 64 * k;
                uint4 v;
                v.x = pkh(pf[2*k].x,   pf[2*k].y);
                v.y = pkh(pf[2*k].z,   pf[2*k].w);
                v.z = pkh(pf[2*k+1].x, pf[2*k+1].y);
                v.w = pkh(pf[2*k+1].z, pf[2*k+1].w);
                *(uint4*)&xt[row * 8] = v;
            }
        };
        auto project = [&](int wi) {
            _Float16* sp = &spre[(wi & 1) * 12288];
            for (int tt = 0; tt < 8; ++tt) {
                const int wl = d ? (7 - tt) : tt;
                const int base0 = (q * 8) * 128 + s16 * 8 + wl;
                f16x8 B0, B1;
                #pragma unroll
                for (int e = 0; e < 8; ++e) {
                    B0[e] = xt[base0 + e * 128];
                    B1[e] = xt[base0 + e * 128 + 4096];
                }
                #pragma unroll
                for (int gt = 0; gt < 6; ++gt) {
                    f32x4 acc = {biasC[gt][0], biasC[gt][1], biasC[gt][2], biasC[gt][3]};
                    acc = __builtin_amdgcn_mfma_f32_16x16x32_f16(W2A[gt][0], B0, acc, 0, 0, 0);
                    acc = __builtin_amdgcn_mfma_f32_16x16x32_f16(W2A[gt][1], B1, acc, 0, 0, 0);
                    uint2 v; v.x = pkh(acc[0], acc[1]); v.y = pkh(acc[2], acc[3]);
                    const int col = (gt * 16 + 4 * q) ^ ((s16 & 7) << 2);
                    *(uint2*)&sp[(tt * 16 + s16) * 96 + col] = v;
                }
            }
        };

        load_win(0);
        #pragma unroll 1
        for (int i = 0; i < 20; ++i) {
            write_xt();
            project(i);
            if (i + 1 < 20) load_win(i + 1);
            BARX();
        }
    } else {
        const _Float16* whh2 = (const _Float16*)((const char*)wsv + WS_WHH2_OFF)
                               + (size_t)d * 96 * 32;
        f16x8 whhA[6];
        #pragma unroll
        for (int gt = 0; gt < 6; ++gt)
            whhA[gt] = *(const f16x8*)&whh2[(gt * 16 + s16) * 32 + q * 8];
        const float* bias = (const float*)((const char*)wsv + WS_BIAS_OFF) + d * 128;
        float bhN[2][4];
        #pragma unroll
        for (int jh = 0; jh < 2; ++jh)
            #pragma unroll
            for (int r = 0; r < 4; ++r)
                bhN[jh][r] = bias[96 + jh * 16 + 4 * q + r];

        float* ob = out + ((size_t)b * 64 + d * 32) * HWSTRIDE + (size_t)(h0 + s16) * 160;
        f16x8 hB = {};
        f16x8 hB8[8];
        float hprev[8];
        #pragma unroll
        for (int uu = 0; uu < 8; ++uu) hprev[uu] = 0.f;

        int spcol[6];
        #pragma unroll
        for (int gt = 0; gt < 6; ++gt)
            spcol[gt] = (gt * 16 + 4 * q) ^ ((s16 & 7) << 2);

        typedef _Float16 f16x4l __attribute__((ext_vector_type(4)));
        #pragma unroll 1
        for (int i = 0; i < 20; ++i) {
            BARX();
            const _Float16* sp = &spre[(i & 1) * 12288];
            f16x4l pg[4][6];
            #pragma unroll
            for (int tt = 0; tt < 8; ++tt) {
                if ((tt & 3) == 0) {
                    #pragma unroll
                    for (int t4 = 0; t4 < 4; ++t4)
                        #pragma unroll
                        for (int gt = 0; gt < 6; ++gt)
                            pg[t4][gt] = *(const f16x4l*)
                                &sp[((tt + t4) * 16 + s16) * 96 + spcol[gt]];
                }
                const f16x4l p0 = pg[tt & 3][0], p1 = pg[tt & 3][1];
                const f16x4l p2 = pg[tt & 3][2], p3 = pg[tt & 3][3];
                const f16x4l p4 = pg[tt & 3][4], p5 = pg[tt & 3][5];
                f32x4 aR0 = {(float)p0[0], (float)p0[1], (float)p0[2], (float)p0[3]};
                f32x4 aR1 = {(float)p1[0], (float)p1[1], (float)p1[2], (float)p1[3]};
                f32x4 aZ0 = {(float)p2[0], (float)p2[1], (float)p2[2], (float)p2[3]};
                f32x4 aZ1 = {(float)p3[0], (float)p3[1], (float)p3[2], (float)p3[3]};
                f32x4 aN0 = {bhN[0][0], bhN[0][1], bhN[0][2], bhN[0][3]};
                f32x4 aN1 = {bhN[1][0], bhN[1][1], bhN[1][2], bhN[1][3]};
                aR0 = __builtin_amdgcn_mfma_f32_16x16x32_f16(whhA[0], hB, aR0, 0, 0, 0);
                aR1 = __builtin_amdgcn_mfma_f32_16x16x32_f16(whhA[1], hB, aR1, 0, 0, 0);
                aZ0 = __builtin_amdgcn_mfma_f32_16x16x32_f16(whhA[2], hB, aZ0, 0, 0, 0);
                aZ1 = __builtin_amdgcn_mfma_f32_16x16x32_f16(whhA[3], hB, aZ1, 0, 0, 0);
                aN0 = __builtin_amdgcn_mfma_f32_16x16x32_f16(whhA[4], hB, aN0, 0, 0, 0);
                aN1 = __builtin_amdgcn_mfma_f32_16x16x32_f16(whhA[5], hB, aN1, 0, 0, 0);
                float hn[8];
                #pragma unroll
                for (int r = 0; r < 4; ++r) {
                    const float rr = __builtin_amdgcn_rcpf(1.f + __expf(-aR0[r]));
                    const float zz = __builtin_amdgcn_rcpf(1.f + __expf(-aZ0[r]));
                    float ta = fmaf(rr, aN0[r], (float)p4[r]);
                    ta = fminf(fmaxf(ta, -15.f), 15.f);
                    const float e2 = __expf(2.f * ta);
                    const float nn = (e2 - 1.f) * __builtin_amdgcn_rcpf(e2 + 1.f);
                    hn[r] = (1.f - zz) * nn + zz * hprev[r];
                }
                #pragma unroll
                for (int r = 0; r < 4; ++r) {
                    const float rr = __builtin_amdgcn_rcpf(1.f + __expf(-aR1[r]));
                    const float zz = __builtin_amdgcn_rcpf(1.f + __expf(-aZ1[r]));
                    float ta = fmaf(rr, aN1[r], (float)p5[r]);
                    ta = fminf(fmaxf(ta, -15.f), 15.f);
                    const float e2 = __expf(2.f * ta);
                    const float nn = (e2 - 1.f) * __builtin_amdgcn_rcpf(e2 + 1.f);
                    hn[4 + r] = (1.f - zz) * nn + zz * hprev[4 + r];
                }
                {
                    uint4 hu;
                    hu.x = pkh(hn[0], hn[1]); hu.y = pkh(hn[2], hn[3]);
                    hu.z = pkh(hn[4], hn[5]); hu.w = pkh(hn[6], hn[7]);
                    hB = __builtin_bit_cast(f16x8, hu);
                }
                hB8[tt] = hB;
                #pragma unroll
                for (int uu = 0; uu < 8; ++uu) hprev[uu] = hn[uu];
            }
            {
                const int w0 = d ? (152 - 8 * i) : (8 * i);
                #pragma unroll
                for (int e = 0; e < 8; ++e) {
                    const int j = (e >> 2) * 16 + 4 * q + (e & 3);
                    float* pw = ob + (size_t)j * HWSTRIDE + w0;
                    if (d == 0) {
                        *(float4*)(pw) = make_float4((float)hB8[0][e], (float)hB8[1][e],
                                                     (float)hB8[2][e], (float)hB8[3][e]);
                        *(float4*)(pw + 4) = make_float4((float)hB8[4][e], (float)hB8[5][e],
                                                         (float)hB8[6][e], (float)hB8[7][e]);
                    } else {
                        *(float4*)(pw) = make_float4((float)hB8[7][e], (float)hB8[6][e],
                                                     (float)hB8[5][e], (float)hB8[4][e]);
                        *(float4*)(pw + 4) = make_float4((float)hB8[3][e], (float)hB8[2][e],
                                                         (float)hB8[1][e], (float)hB8[0][e]);
                    }
                }
            }
        }
    }
}

extern "C" void kernel_launch(void* const* d_in, const int* in_sizes, int n_in,
                              void* d_out, int out_size, void* d_ws, size_t ws_size,
                              hipStream_t stream) {
    (void)in_sizes; (void)n_in; (void)out_size;
    fold_weights<<<dim3(74), dim3(256), 0, stream>>>(
        (const float*)d_in[1],  // conv_w
        (const float*)d_in[2],  // conv_b
        (const float*)d_in[3],  // wih_f
        (const float*)d_in[5],  // bih_f
        (const float*)d_in[6],  // bhh_f
        (const float*)d_in[7],  // wih_b
        (const float*)d_in[9],  // bih_b
        (const float*)d_in[10], // bhh_b
        (const float*)d_in[4],  // whh_f
        (const float*)d_in[8],  // whh_b
        d_ws);
    const size_t need = (size_t)WS_X16_OFF + (size_t)192 * 160 * 1024 * 2;
    if (ws_size >= need) {
        _Float16* x16 = (_Float16*)((char*)d_ws + WS_X16_OFF);
        xpose2<<<dim3(1920), dim3(256), 0, stream>>>((const float*)d_in[0], x16);
        gru_fused14<<<dim3(384), dim3(64), 0, stream>>>(x16, d_ws, (float*)d_out);
    } else {
        gru_fused8<<<dim3(384), dim3(128), 0, stream>>>(
            (const float*)d_in[0], d_ws, (float*)d_out);
    }
}